// Round 1
// baseline (871.357 us; speedup 1.0000x reference)
//
#include <hip/hip_runtime.h>

// Problem constants (from reference): B=32, S=4096, D=1024, fp32, mask int32.
#define BATCH 32
#define SEQ   4096
#define DIM   1024
#define NEGV  (-1e37f)
#define SPLIT 32              // S-chunks for the V pass
#define ROWS_PER_BLOCK 64     // K-rows per block in QK pass

// ---------------- Kernel 1: masked logits = q . k ----------------
// grid (B, S/ROWS_PER_BLOCK), block 256 (4 waves). One wave per K-row.
__global__ __launch_bounds__(256) void qk_logits(
    const float* __restrict__ K, const float* __restrict__ Q,
    const int* __restrict__ mask, float* __restrict__ logits) {
  const int b    = blockIdx.x;
  const int s0   = blockIdx.y * ROWS_PER_BLOCK;
  const int tid  = threadIdx.x;
  const int lane = tid & 63;
  const int wave = tid >> 6;  // 0..3

  // q fragment: lane holds d = {lane*4, 256+lane*4, 512+lane*4, 768+lane*4}
  const float4* q4 = (const float4*)(Q + (size_t)b * DIM);
  const float4 q0 = q4[lane];
  const float4 q1 = q4[64 + lane];
  const float4 q2 = q4[128 + lane];
  const float4 q3 = q4[192 + lane];

  const int rows_per_wave = ROWS_PER_BLOCK / 4;  // 16
  for (int r = 0; r < rows_per_wave; ++r) {
    const int s = s0 + wave * rows_per_wave + r;
    // wave-uniform mask check: skip the 4 KB K-row read entirely when masked
    if (mask[(size_t)b * SEQ + s] == 0) {
      if (lane == 0) logits[(size_t)b * SEQ + s] = NEGV;
      continue;
    }
    const float4* k4 = (const float4*)(K + ((size_t)b * SEQ + s) * DIM);
    const float4 k0 = k4[lane];
    const float4 k1 = k4[64 + lane];
    const float4 k2 = k4[128 + lane];
    const float4 k3 = k4[192 + lane];
    float acc = q0.x*k0.x + q0.y*k0.y + q0.z*k0.z + q0.w*k0.w;
    acc      += q1.x*k1.x + q1.y*k1.y + q1.z*k1.z + q1.w*k1.w;
    acc      += q2.x*k2.x + q2.y*k2.y + q2.z*k2.z + q2.w*k2.w;
    acc      += q3.x*k3.x + q3.y*k3.y + q3.z*k3.z + q3.w*k3.w;
    // wave64 shuffle reduction
    for (int off = 32; off > 0; off >>= 1)
      acc += __shfl_down(acc, off, 64);
    if (lane == 0) logits[(size_t)b * SEQ + s] = acc;
  }
}

// ---------------- Kernel 2: per-batch softmax, weights in place ----------------
// grid B, block 256. Each thread owns 16 strided positions.
__global__ __launch_bounds__(256) void softmax_w(float* __restrict__ lw) {
  const int b   = blockIdx.x;
  const int tid = threadIdx.x;
  const int lane = tid & 63;
  const int wave = tid >> 6;
  __shared__ float wmax[4];
  __shared__ float wsum[4];

  float lv[16];
  float lm = -3.4e38f;
  #pragma unroll
  for (int i = 0; i < 16; ++i) {
    lv[i] = lw[(size_t)b * SEQ + tid + i * 256];
    lm = fmaxf(lm, lv[i]);
  }
  for (int off = 32; off > 0; off >>= 1)
    lm = fmaxf(lm, __shfl_down(lm, off, 64));
  if (lane == 0) wmax[wave] = lm;
  __syncthreads();
  const float m = fmaxf(fmaxf(wmax[0], wmax[1]), fmaxf(wmax[2], wmax[3]));

  float e[16];
  float ls = 0.f;
  #pragma unroll
  for (int i = 0; i < 16; ++i) {
    e[i] = __expf(lv[i] - m);   // exp(-1e37 - m) underflows to exactly 0
    ls += e[i];
  }
  for (int off = 32; off > 0; off >>= 1)
    ls += __shfl_down(ls, off, 64);
  if (lane == 0) wsum[wave] = ls;
  __syncthreads();
  const float inv = 1.0f / (wsum[0] + wsum[1] + wsum[2] + wsum[3]);
  #pragma unroll
  for (int i = 0; i < 16; ++i)
    lw[(size_t)b * SEQ + tid + i * 256] = e[i] * inv;  // in-place: own indices only
}

// ---------------- Kernel 3: partial weighted V accumulation ----------------
// grid (B, SPLIT), block 256. Thread owns 4 contiguous d (float4); loop over S-chunk.
__global__ __launch_bounds__(256) void wv_partial(
    const float* __restrict__ V, const float* __restrict__ w,
    float* __restrict__ part) {
  const int b   = blockIdx.x;
  const int c   = blockIdx.y;
  const int tid = threadIdx.x;
  const int s0  = c * (SEQ / SPLIT);
  float4 acc = make_float4(0.f, 0.f, 0.f, 0.f);
  for (int i = 0; i < SEQ / SPLIT; ++i) {
    const int s = s0 + i;
    const float wi = w[(size_t)b * SEQ + s];  // same addr all threads -> broadcast
    if (wi != 0.0f) {                          // block-uniform: skip masked V row
      const float4 v = ((const float4*)(V + ((size_t)b * SEQ + s) * DIM))[tid];
      acc.x += wi * v.x; acc.y += wi * v.y; acc.z += wi * v.z; acc.w += wi * v.w;
    }
  }
  ((float4*)(part + ((size_t)b * SPLIT + c) * DIM))[tid] = acc;
}

// ---------------- Kernel 4: reduce partials -> out ----------------
// grid B, block 256.
__global__ __launch_bounds__(256) void reduce_out(
    const float* __restrict__ part, float* __restrict__ out) {
  const int b   = blockIdx.x;
  const int tid = threadIdx.x;
  float4 acc = make_float4(0.f, 0.f, 0.f, 0.f);
  for (int c = 0; c < SPLIT; ++c) {
    const float4 p = ((const float4*)(part + ((size_t)b * SPLIT + c) * DIM))[tid];
    acc.x += p.x; acc.y += p.y; acc.z += p.z; acc.w += p.w;
  }
  ((float4*)(out + (size_t)b * DIM))[tid] = acc;
}

extern "C" void kernel_launch(void* const* d_in, const int* in_sizes, int n_in,
                              void* d_out, int out_size, void* d_ws, size_t ws_size,
                              hipStream_t stream) {
  const float* keys    = (const float*)d_in[0];
  const float* queries = (const float*)d_in[1];
  const float* values  = (const float*)d_in[2];
  const int*   mask    = (const int*)d_in[3];
  float* out = (float*)d_out;

  // ws layout: [logits/weights: B*S floats][partials: B*SPLIT*D floats]
  float* lw   = (float*)d_ws;
  float* part = lw + (size_t)BATCH * SEQ;

  qk_logits<<<dim3(BATCH, SEQ / ROWS_PER_BLOCK), 256, 0, stream>>>(keys, queries, mask, lw);
  softmax_w<<<BATCH, 256, 0, stream>>>(lw);
  wv_partial<<<dim3(BATCH, SPLIT), 256, 0, stream>>>(values, lw, part);
  reduce_out<<<BATCH, 256, 0, stream>>>(part, out);
}